// Round 9
// baseline (294.090 us; speedup 1.0000x reference)
//
#include <hip/hip_runtime.h>
#include <math.h>

typedef unsigned int uint;
typedef unsigned short ushort;

typedef __bf16 bf16x8 __attribute__((ext_vector_type(8)));
typedef float f32x4 __attribute__((ext_vector_type(4)));

#define MAXNB 512  // n < 65536 -> NB = ceil(n/128) <= 512

// ---------------- bf16 helpers (RNE pack, shift unpack) ----------------

__device__ inline uint bf16rne(float f) {
    uint u = __float_as_uint(f);
    uint r = ((u >> 16) & 1u) + 0x7fffu;
    return (u + r) >> 16;
}
__device__ inline uint packbf2(float a, float b) {
    return bf16rne(a) | (bf16rne(b) << 16);
}
__device__ inline float unlo(uint v) { return __uint_as_float(v << 16); }
__device__ inline float unhi(uint v) { return __uint_as_float(v & 0xffff0000u); }

// ---------------- graph prep: tile-major bucketed CSR build ----------------
// bucket = dst>>7; tile = 2048 edges. tmp is TILE-major (dense writes per tile,
// no cross-XCD false sharing); per-bucket runs inside a tile are read back by
// block-per-bucket phase-2 kernels (scattered reads are cheap, scattered writes are not).

// per-tile LDS histogram + scan; emits per-edge rank and S[t][be] = within-tile start
__global__ __launch_bounds__(256) void k_hist(const int* __restrict__ dst, int E, int NB1,
                                              ushort* __restrict__ rank,
                                              ushort* __restrict__ S) {
    __shared__ int hist[MAXNB];
    __shared__ int scn[MAXNB];
    int tid = threadIdx.x, t = blockIdx.x;
    hist[tid] = 0; hist[tid + 256] = 0;
    __syncthreads();
    int e0 = t * 2048;
#pragma unroll
    for (int i = 0; i < 8; ++i) {
        int e = e0 + i * 256 + tid;
        if (e < E) rank[e] = (ushort)atomicAdd(&hist[dst[e] >> 7], 1);  // LDS atomic
    }
    __syncthreads();
    int a0 = hist[tid], a1 = hist[tid + 256];
    int c0 = a0, c1 = a1;                        // inclusive scan (Hillis-Steele, 512)
    scn[tid] = c0; scn[tid + 256] = c1;
    __syncthreads();
    for (int off = 1; off < 512; off <<= 1) {
        int v0 = (tid >= off) ? scn[tid - off] : 0;
        int v1 = (tid + 256 >= off) ? scn[tid + 256 - off] : 0;
        __syncthreads();
        c0 += v0; c1 += v1;
        scn[tid] = c0; scn[tid + 256] = c1;
        __syncthreads();
    }
    int NB = NB1 - 1;
    if (tid < NB) S[(size_t)t * NB1 + tid] = (ushort)(c0 - a0);          // exclusive
    if (tid + 256 < NB) S[(size_t)t * NB1 + tid + 256] = (ushort)(c1 - a1);
    if (tid == 0) S[(size_t)t * NB1 + NB] = (ushort)scn[511];            // tile total
}

// wave per bucket: T[be] = total edges of bucket (sum of run lengths over tiles)
__global__ __launch_bounds__(64) void k_tsum(const ushort* __restrict__ S, int NB1, int NT1,
                                             int* __restrict__ T) {
    int be = blockIdx.x, lane = threadIdx.x;
    int s = 0;
    for (int t = lane; t < NT1; t += 64) {
        size_t base = (size_t)t * NB1;
        s += (int)S[base + be + 1] - (int)S[base + be];
    }
#pragma unroll
    for (int d = 32; d; d >>= 1) s += __shfl_down(s, d);
    if (lane == 0) T[be] = s;
}

// one wave: cbase = exclscan(T + 2048) (csr layout; 2048 >= max node pad 128*15)
__global__ __launch_bounds__(64) void k_bscan(const int* __restrict__ T, int NB,
                                              int* __restrict__ cbase) {
    int lane = threadIdx.x;
    int carry = 0;
    for (int b0 = 0; b0 < NB; b0 += 64) {
        int idx = b0 + lane;
        int t = (idx < NB) ? T[idx] + 2048 : 0;
        int s = t;
#pragma unroll
        for (int d = 1; d < 64; d <<= 1) {
            int o = __shfl_up(s, d);
            if (lane >= d) s += o;
        }
        if (idx < NB) cbase[idx] = carry + s - t;
        carry += __shfl(s, 63);
    }
}

// dense scatter into tile-major tmp; entry = {src:16 | dst&127 : upper}
__global__ void k_place(const int* __restrict__ src, const int* __restrict__ dst, int E,
                        int NB1, const ushort* __restrict__ rank,
                        const ushort* __restrict__ S, uint* __restrict__ tmp) {
    int e = blockIdx.x * blockDim.x + threadIdx.x;
    if (e >= E) return;
    int d = dst[e];
    int t = e >> 11, be = d >> 7;
    int pos = t * 2048 + (int)S[(size_t)t * NB1 + be] + (int)rank[e];
    tmp[pos] = (uint)src[e] | ((uint)(d & 127) << 16);
}

// block per bucket: node counts (LDS) -> 16-padded scan -> offs/ends/dinv
__global__ __launch_bounds__(256) void k_p2a(const uint* __restrict__ tmp,
                                             const ushort* __restrict__ S, int NB1, int NT1,
                                             const int* __restrict__ cbase,
                                             int* __restrict__ offs, int* __restrict__ ends,
                                             float* __restrict__ dinv, int n) {
    __shared__ int lcnt[128];
    __shared__ int sinc[128];
    int be = blockIdx.x, tid = threadIdx.x;
    if (tid < 128) lcnt[tid] = 0;
    __syncthreads();
    for (int t = tid; t < NT1; t += 256) {
        size_t base = (size_t)t * NB1;
        int st = t * 2048 + (int)S[base + be];
        int len = (int)S[base + be + 1] - (int)S[base + be];
        for (int k = 0; k < len; ++k)
            atomicAdd(&lcnt[(tmp[st + k] >> 16) & 127], 1);
    }
    __syncthreads();
    if (tid < 128) {
        int cp = (lcnt[tid] + 15) & ~15;   // pad to 16 (agg K=16)
        int lane = tid & 63;
        int s = cp;
#pragma unroll
        for (int d = 1; d < 64; d <<= 1) {
            int o = __shfl_up(s, d);
            if (lane >= d) s += o;
        }
        sinc[tid] = s;  // inclusive within wave
    }
    __syncthreads();
    if (tid < 128) {
        int c = lcnt[tid];
        int cp = (c + 15) & ~15;
        int base = (tid >= 64) ? sinc[63] : 0;
        int og = cbase[be] + base + sinc[tid] - cp;
        int i = be * 128 + tid;
        if (i < n) {
            offs[i] = og;
            ends[i] = og + c;
            dinv[i] = rsqrtf((float)(c + 1));  // +1 self loop
        }
    }
}

// block per bucket: final scatter; all writes land in this bucket's csr window
// (single block = single XCD -> no false sharing). csr entry = {src:16 | bf16(w):16}.
__global__ __launch_bounds__(256) void k_p2b(const uint* __restrict__ tmp,
                                             const ushort* __restrict__ S, int NB1, int NT1,
                                             const int* __restrict__ offs,
                                             const float* __restrict__ dinv,
                                             uint* __restrict__ csr) {
    __shared__ int cur[128];
    int be = blockIdx.x, tid = threadIdx.x;
    if (tid < 128) cur[tid] = 0;
    __syncthreads();
    for (int t = tid; t < NT1; t += 256) {
        size_t base = (size_t)t * NB1;
        int st = t * 2048 + (int)S[base + be];
        int len = (int)S[base + be + 1] - (int)S[base + be];
        for (int k = 0; k < len; ++k) {
            uint v = tmp[st + k];
            int s = (int)(v & 0xffffu);
            int dl = (int)((v >> 16) & 127u);
            int d = be * 128 + dl;
            int r = atomicAdd(&cur[dl], 1);  // LDS atomic
            uint wb = bf16rne(dinv[s] * dinv[d]) << 16;
            csr[offs[d] + r] = (uint)s | wb;
        }
    }
}

// fused weight prep: WT0/WT1 = W^T bf16 [128x128]; WT2 = padded W2^T bf16 [64x128]
__global__ void k_prep(const float* __restrict__ W0, const float* __restrict__ W1,
                       const float* __restrict__ W2, ushort* __restrict__ WT0,
                       ushort* __restrict__ WT1, ushort* __restrict__ WT2) {
    int idx = blockIdx.x * blockDim.x + threadIdx.x;
    if (idx < 16384) {
        int c = idx >> 7, k = idx & 127;
        WT0[idx] = (ushort)bf16rne(W0[k * 128 + c]);
        WT1[idx] = (ushort)bf16rne(W1[k * 128 + c]);
    } else if (idx < 16384 + 8192) {
        int j = idx - 16384;
        int c = j >> 7, k = j & 127;
        WT2[j] = (c < 40) ? (ushort)bf16rne(W2[k * 40 + c]) : (ushort)0;
    }
}

// ---------------- MFMA GEMM: Hb[n x F](bf16) = X[n x 128] @ W, WT = W^T[F x 128] ----
// wave = 16 rows x F cols; A frag A[m=lane&15][k=quad*8+j] (16B global loads);
// B frag = WT rows (B^T pattern); D: col=lane&15, row=quad*4+reg. No LDS.
template <int F, bool F32IN>
__global__ __launch_bounds__(256) void k_mgemm(const void* __restrict__ Xv,
                                               const __bf16* __restrict__ WT,
                                               ushort* __restrict__ Hb, int n) {
    constexpr int NT = F / 16;  // 16-col tiles
    int lane = threadIdx.x & 63;
    int wv = threadIdx.x >> 6;
    int rbase = blockIdx.x * 64 + wv * 16;
    if (rbase >= n) return;  // n % 16 == 0: strips fully valid or fully absent
    int m = lane & 15, quad = lane >> 4;

    bf16x8 a[4];
    if (F32IN) {
        const float* xrow = (const float*)Xv + (size_t)(rbase + m) * 128 + quad * 8;
#pragma unroll
        for (int ks = 0; ks < 4; ++ks) {
            float4 lo = *(const float4*)(xrow + ks * 32);
            float4 hi = *(const float4*)(xrow + ks * 32 + 4);
            union { ushort u[8]; bf16x8 v; } cv;
            cv.u[0] = (ushort)bf16rne(lo.x); cv.u[1] = (ushort)bf16rne(lo.y);
            cv.u[2] = (ushort)bf16rne(lo.z); cv.u[3] = (ushort)bf16rne(lo.w);
            cv.u[4] = (ushort)bf16rne(hi.x); cv.u[5] = (ushort)bf16rne(hi.y);
            cv.u[6] = (ushort)bf16rne(hi.z); cv.u[7] = (ushort)bf16rne(hi.w);
            a[ks] = cv.v;
        }
    } else {
        const __bf16* xrow = (const __bf16*)Xv + (size_t)(rbase + m) * 128 + quad * 8;
#pragma unroll
        for (int ks = 0; ks < 4; ++ks) a[ks] = *(const bf16x8*)(xrow + ks * 32);
    }

    f32x4 acc[NT];
#pragma unroll
    for (int t = 0; t < NT; ++t) acc[t] = (f32x4){0.f, 0.f, 0.f, 0.f};

#pragma unroll
    for (int t = 0; t < NT; ++t) {
        const __bf16* wrow = WT + (size_t)(t * 16 + m) * 128 + quad * 8;
#pragma unroll
        for (int ks = 0; ks < 4; ++ks) {
            bf16x8 b = *(const bf16x8*)(wrow + ks * 32);
            acc[t] = __builtin_amdgcn_mfma_f32_16x16x32_bf16(a[ks], b, acc[t], 0, 0, 0);
        }
    }

#pragma unroll
    for (int t = 0; t < NT; ++t) {
#pragma unroll
        for (int r = 0; r < 4; ++r) {
            int row = rbase + quad * 4 + r;
            Hb[(size_t)row * F + t * 16 + m] = (ushort)bf16rne(acc[t][r]);
        }
    }
}

// ---------------- aggregation: y[i] = relu( sum_e w_e h[src_e] + dinv_i^2 h[i] + b ) --------
// one wave per node; lane = 2 bf16 features (F=128); fp32 accumulate; bf16 packed out.
// K=16 gathers in flight; chunk = 16 uint entries {src|w} = four aligned 16B broadcast
// loads; regions padded to 16 with zeros -> no masking.
__global__ __launch_bounds__(256) void k_agg128(const uint* __restrict__ hb,
                                                const int* __restrict__ offs,
                                                const int* __restrict__ ends,
                                                const uint* __restrict__ csr,
                                                const float* __restrict__ dinv,
                                                const float* __restrict__ bias,
                                                uint* __restrict__ out, int n) {
    int wid = (blockIdx.x * blockDim.x + threadIdx.x) >> 6;
    int lane = threadIdx.x & 63;
    if (wid >= n) return;
    float di = dinv[wid];
    uint t0 = hb[((size_t)wid << 6) + lane];
    float2 acc = make_float2(unlo(t0) * di * di, unhi(t0) * di * di);
    int e0 = offs[wid];                       // multiple of 16
    int nchunk = (ends[wid] - e0 + 15) >> 4;
    const uint4* csrv = (const uint4*)(csr + e0);

    uint Pa[16], Pb[16];                      // packed {src | w_bf16}
    uint Ga[16], Gb[16];

    auto loadP = [&](int c, uint* p) {        // speculative final load: zero-pad/next region
#pragma unroll
        for (int q = 0; q < 4; ++q) {
            uint4 v = csrv[4 * c + q];
            p[4 * q] = v.x; p[4 * q + 1] = v.y; p[4 * q + 2] = v.z; p[4 * q + 3] = v.w;
        }
    };
    auto gatherK = [&](const uint* p, uint* g) {
#pragma unroll
        for (int j = 0; j < 16; ++j) g[j] = hb[((size_t)(p[j] & 0xffffu) << 6) + lane];
    };
    auto fmaK = [&](const uint* p, const uint* g) {
#pragma unroll
        for (int j = 0; j < 16; ++j) {
            float w = unhi(p[j]);
            acc.x = fmaf(w, unlo(g[j]), acc.x);
            acc.y = fmaf(w, unhi(g[j]), acc.y);
        }
    };

    if (nchunk > 0) {
        loadP(0, Pa);
        gatherK(Pa, Ga);
        loadP(1, Pb);
        int c = 0;
        while (true) {
            gatherK(Pb, Gb);   // chunk c+1 (entries pre-loaded)
            fmaK(Pa, Ga);      // chunk c (gathers issued an iter ago)
            if (++c >= nchunk) break;
            loadP(c + 1, Pa);
            gatherK(Pa, Ga);
            fmaK(Pb, Gb);
            if (++c >= nchunk) break;
            loadP(c + 1, Pb);
        }
    }

    float2 b = ((const float2*)bias)[lane];
    out[((size_t)wid << 6) + lane] =
        packbf2(fmaxf(acc.x + b.x, 0.f), fmaxf(acc.y + b.y, 0.f));
}

// final layer: F=40 (padded to 64 with exact zeros, bf16), fused bias+relu+log_softmax
__global__ __launch_bounds__(256) void k_agg40(const ushort* __restrict__ hb,
                                               const int* __restrict__ offs,
                                               const int* __restrict__ ends,
                                               const uint* __restrict__ csr,
                                               const float* __restrict__ dinv,
                                               const float* __restrict__ bias,
                                               float* __restrict__ out, int n) {
    int wid = (blockIdx.x * blockDim.x + threadIdx.x) >> 6;
    int lane = threadIdx.x & 63;
    if (wid >= n) return;
    float di = dinv[wid];
    float acc = __uint_as_float(((uint)hb[((size_t)wid << 6) + lane]) << 16) * di * di;
    int e0 = offs[wid];
    int nchunk = (ends[wid] - e0 + 7) >> 3;   // K=8; 16-padding is a multiple of 8
    const uint4* csrv = (const uint4*)(csr + e0);

    uint Pa[8], Pb[8];
    uint Ga[8], Gb[8];

    auto loadP = [&](int c, uint* p) {
        uint4 v0 = csrv[2 * c];
        uint4 v1 = csrv[2 * c + 1];
        p[0] = v0.x; p[1] = v0.y; p[2] = v0.z; p[3] = v0.w;
        p[4] = v1.x; p[5] = v1.y; p[6] = v1.z; p[7] = v1.w;
    };
    auto gatherK = [&](const uint* p, uint* g) {
#pragma unroll
        for (int j = 0; j < 8; ++j) g[j] = (uint)hb[((size_t)(p[j] & 0xffffu) << 6) + lane];
    };
    auto fmaK = [&](const uint* p, const uint* g) {
#pragma unroll
        for (int j = 0; j < 8; ++j) {
            float w = unhi(p[j]);
            acc = fmaf(w, __uint_as_float(g[j] << 16), acc);
        }
    };

    if (nchunk > 0) {
        loadP(0, Pa);
        gatherK(Pa, Ga);
        loadP(1, Pb);
        int c = 0;
        while (true) {
            gatherK(Pb, Gb);
            fmaK(Pa, Ga);
            if (++c >= nchunk) break;
            loadP(c + 1, Pa);
            gatherK(Pa, Ga);
            fmaK(Pb, Gb);
            if (++c >= nchunk) break;
            loadP(c + 1, Pb);
        }
    }

    float v = (lane < 40) ? fmaxf(acc + bias[lane], 0.f) : -INFINITY;
    float m = v;
#pragma unroll
    for (int d = 32; d; d >>= 1) m = fmaxf(m, __shfl_xor(m, d));
    float ex = (lane < 40) ? expf(v - m) : 0.f;
    float ssum = ex;
#pragma unroll
    for (int d = 32; d; d >>= 1) ssum += __shfl_xor(ssum, d);
    if (lane < 40) out[wid * 40 + lane] = v - m - logf(ssum);
}

// ---------------- launch ----------------

extern "C" void kernel_launch(void* const* d_in, const int* in_sizes, int n_in,
                              void* d_out, int out_size, void* d_ws, size_t ws_size,
                              hipStream_t stream) {
    const float* x  = (const float*)d_in[0];
    const int*   ei = (const int*)d_in[1];
    const float* W0 = (const float*)d_in[2];
    const float* b0 = (const float*)d_in[3];
    const float* W1 = (const float*)d_in[4];
    const float* b1 = (const float*)d_in[5];
    const float* W2 = (const float*)d_in[6];
    const float* b2 = (const float*)d_in[7];
    float* out = (float*)d_out;

    int n = in_sizes[0] / 128;
    int E = in_sizes[1] / 2;
    const int* srcv = ei;
    const int* dstv = ei + E;
    int NB  = (n + 127) / 128;     // buckets (dst>>7), <= 512
    int NB1 = NB + 1;
    int NT1 = (E + 2047) / 2048;   // tiles
    size_t csr_elems = (size_t)E + 2048 * (size_t)NB + 64;

    char* w = (char*)d_ws;
    auto alloc = [&](size_t bytes) {
        char* p = w;
        w += (bytes + 255) & ~(size_t)255;
        return p;
    };
    uint*   csr    = (uint*)alloc(csr_elems * 4);            // memset 0 (pads stay zero)
    ushort* S      = (ushort*)alloc((size_t)NT1 * NB1 * 2);
    ushort* rank   = (ushort*)alloc((size_t)E * 2);
    uint*   tmp    = (uint*)alloc((size_t)NT1 * 2048 * 4);
    int*    T      = (int*)alloc((size_t)NB * 4);
    int*    cbase  = (int*)alloc((size_t)NB * 4);
    int*    offs   = (int*)alloc((size_t)n * 4);
    int*    ends   = (int*)alloc((size_t)n * 4);
    float*  dinv   = (float*)alloc((size_t)n * 4);
    uint*   xb     = (uint*)alloc((size_t)n * 64 * 4);   // n x 128 bf16 (agg out)
    uint*   hA     = (uint*)alloc((size_t)n * 64 * 4);   // n x 128 bf16 (gemm out)
    ushort* hC     = (ushort*)alloc((size_t)n * 64 * 2); // n x 64 bf16
    ushort* WT0    = (ushort*)alloc(128 * 128 * 2);
    ushort* WT1    = (ushort*)alloc(128 * 128 * 2);
    ushort* WT2    = (ushort*)alloc(64 * 128 * 2);

    hipMemsetAsync(csr, 0, csr_elems * 4, stream);

    k_hist<<<NT1, 256, 0, stream>>>(dstv, E, NB1, rank, S);
    k_tsum<<<NB, 64, 0, stream>>>(S, NB1, NT1, T);
    k_bscan<<<1, 64, 0, stream>>>(T, NB, cbase);
    k_place<<<(E + 255) / 256, 256, 0, stream>>>(srcv, dstv, E, NB1, rank, S, tmp);
    k_p2a<<<NB, 256, 0, stream>>>(tmp, S, NB1, NT1, cbase, offs, ends, dinv, n);
    k_p2b<<<NB, 256, 0, stream>>>(tmp, S, NB1, NT1, offs, dinv, csr);
    k_prep<<<(16384 + 8192 + 255) / 256, 256, 0, stream>>>(W0, W1, W2, WT0, WT1, WT2);

    int gblocks = (n + 63) / 64;
    int ablocks = (n + 3) / 4;

    // layer 0 (fp32 x read directly)
    k_mgemm<128, true><<<gblocks, 256, 0, stream>>>(x, (const __bf16*)WT0, (ushort*)hA, n);
    k_agg128<<<ablocks, 256, 0, stream>>>(hA, offs, ends, csr, dinv, b0, xb, n);
    // layer 1
    k_mgemm<128, false><<<gblocks, 256, 0, stream>>>(xb, (const __bf16*)WT1, (ushort*)hA, n);
    k_agg128<<<ablocks, 256, 0, stream>>>(hA, offs, ends, csr, dinv, b1, xb, n);
    // layer 2 + log_softmax
    k_mgemm<64, false><<<gblocks, 256, 0, stream>>>(xb, (const __bf16*)WT2, hC, n);
    k_agg40<<<ablocks, 256, 0, stream>>>(hC, offs, ends, csr, dinv, b2, out, n);
}